// Round 16
// baseline (559.915 us; speedup 1.0000x reference)
//
#include <hip/hip_runtime.h>
#include <math.h>

#define BZ   8
#define DDIM 128
#define NN   2048
#define KSEL 30
#define KEEP 1024
#define ROWS 8

// ---------- block reduction (blockDim == 256) ----------
__device__ __forceinline__ double blockReduceD(double x, double* lds) {
  #pragma unroll
  for (int off = 32; off; off >>= 1) x += __shfl_down(x, off, 64);
  int wv = threadIdx.x >> 6;
  __syncthreads();
  if ((threadIdx.x & 63) == 0) lds[wv] = x;
  __syncthreads();
  return lds[0] + lds[1] + lds[2] + lds[3];
}

// ---------- K1: normalize -> fp32 xnT + fp64 row panel; init counter ------
__global__ __launch_bounds__(256) void k_norm(const float* __restrict__ data,
                                              float* __restrict__ xnT,
                                              double* __restrict__ panelD,
                                              unsigned* __restrict__ counter) {
  __shared__ double lds[4];
  __shared__ float msd[2];
  const int blk = blockIdx.x;          // b*128 + d
  const int t = threadIdx.x;
  if (blk == 0 && t == 0) *counter = 0u;   // deterministic init each call
  const float* src = data + (size_t)blk * NN;
  float v[8];
  double s = 0.0, s2 = 0.0;
  #pragma unroll
  for (int q = 0; q < 8; ++q) {
    v[q] = src[t + q * 256];
    double d = (double)v[q];
    s += d;
    s2 = fma(d, d, s2);
  }
  s  = blockReduceD(s, lds);
  s2 = blockReduceD(s2, lds);
  if (t == 0) {
    double mean = s * (1.0 / 2048.0);
    double var = (s2 - s * mean) / 2047.0;
    if (var < 0.0) var = 0.0;
    msd[0] = (float)mean;
    msd[1] = (float)sqrt(var);
  }
  __syncthreads();
  const float mean = msd[0];
  const float den = msd[1] + 1e-6f;
  const int b = blk >> 7, d = blk & 127;
  #pragma unroll
  for (int q = 0; q < 8; ++q) {
    const int n = t + q * 256;
    const float xn = (v[q] - mean) / den;   // fp32 rounding point
    xnT[(size_t)blk * NN + n] = xn;
    panelD[(size_t)(b * 256 + (n >> 3)) * 1024 + d * 8 + (n & 7)] = (double)xn;
  }
}

// ---------- K2: sq[b][n] = sum_d Xn^2 (fp64 chain, fp32 input) ----------
__global__ __launch_bounds__(256) void k_sq(const float* __restrict__ xnT,
                                            double* __restrict__ sq) {
  const int g = blockIdx.x * 256 + threadIdx.x;
  const int b = g >> 11, n = g & 2047;
  const float* X = xnT + (size_t)b * DDIM * NN + n;
  double s = 0.0;
  for (int d = 0; d < DDIM; ++d) {
    double x = (double)X[(size_t)d * NN];
    s = fma(x, x, s);
  }
  sq[g] = s;
}

// ---------- K3: cyclic-halved symmetric fp64 GEMM, SGPR rows (round 9) ----
// Blocks [0,2048): b=blk&7 (XCD pin), g=blk>>3; rows [8g,8g+8), cols cyclic
// window [8g, 8g+1024). Rows from fp64 panel (block-uniform -> s_load, SGPR
// fma operand); cols fp32 float4 + exact widen. Separation-128 antipodal
// tiles: blocks [2048,2304). Proven 130.5 us / absmax 0.0 (rounds 9,12,13).
__global__ __launch_bounds__(256, 4) void k_gemm_sgpr(
    const float* __restrict__ xnT, const double* __restrict__ panelD,
    const double* __restrict__ sq, float* __restrict__ distM) {
  const int t = threadIdx.x;
  if (blockIdx.x < 2048) {
    const int b = blockIdx.x & 7;
    const int g = blockIdx.x >> 3;
    const int i0 = g << 3;
    const int c = (i0 + (t << 2)) & (NN - 1);
    const float*  cp = xnT + (size_t)b * DDIM * NN + c;
    const double* rp = panelD + ((size_t)(b * 256 + g) << 10);
    double acc[ROWS][4];
    #pragma unroll
    for (int r = 0; r < ROWS; ++r)
      #pragma unroll
      for (int q = 0; q < 4; ++q) acc[r][q] = 0.0;
    #pragma unroll 2
    for (int d = 0; d < DDIM; ++d) {
      const float4 c0 = *(const float4*)(cp + ((size_t)d << 11));
      const double cd0 = (double)c0.x, cd1 = (double)c0.y;
      const double cd2 = (double)c0.z, cd3 = (double)c0.w;
      #pragma unroll
      for (int r = 0; r < ROWS; ++r) {
        const double rv = rp[(d << 3) + r];   // uniform -> s_load
        acc[r][0] = fma(rv, cd0, acc[r][0]);
        acc[r][1] = fma(rv, cd1, acc[r][1]);
        acc[r][2] = fma(rv, cd2, acc[r][2]);
        acc[r][3] = fma(rv, cd3, acc[r][3]);
      }
    }
    const double* sqb = sq + (b << 11);
    const double sqc0 = sqb[c], sqc1 = sqb[c + 1], sqc2 = sqb[c + 2], sqc3 = sqb[c + 3];
    float f[ROWS][4];
    #pragma unroll
    for (int r = 0; r < ROWS; ++r) {
      const double sqi = sqb[i0 + r];
      double d2;
      d2 = (sqi + sqc0) - 2.0 * acc[r][0]; if (d2 < 0.0) d2 = 0.0; f[r][0] = (float)sqrt(d2);
      d2 = (sqi + sqc1) - 2.0 * acc[r][1]; if (d2 < 0.0) d2 = 0.0; f[r][1] = (float)sqrt(d2);
      d2 = (sqi + sqc2) - 2.0 * acc[r][2]; if (d2 < 0.0) d2 = 0.0; f[r][2] = (float)sqrt(d2);
      d2 = (sqi + sqc3) - 2.0 * acc[r][3]; if (d2 < 0.0) d2 = 0.0; f[r][3] = (float)sqrt(d2);
      *(float4*)(distM + (((size_t)((b << 11) + i0 + r)) << 11) + c) =
          make_float4(f[r][0], f[r][1], f[r][2], f[r][3]);
    }
    #pragma unroll
    for (int q = 0; q < 4; ++q) {
      float* trow = distM + (((size_t)((b << 11) + c + q)) << 11) + i0;
      *(float4*)(trow)     = make_float4(f[0][q], f[1][q], f[2][q], f[3][q]);
      *(float4*)(trow + 4) = make_float4(f[4][q], f[5][q], f[6][q], f[7][q]);
    }
  } else {
    const int a = (blockIdx.x - 2048) * 4 + (t >> 6);
    const int b = a & 7;
    const int g = a >> 3;
    const int i0 = g << 3;
    const int j0 = i0 + 1024;
    const int l = t & 63;
    const int r = l >> 3, q = l & 7;
    const double* rp = panelD + ((size_t)(b * 256 + g) << 10);
    const float*  cp = xnT + (size_t)b * DDIM * NN + j0 + q;
    double acc = 0.0;
    for (int d = 0; d < DDIM; ++d)
      acc = fma(rp[(d << 3) + r], (double)cp[(size_t)d << 11], acc);
    const double* sqb = sq + (b << 11);
    double d2 = (sqb[i0 + r] + sqb[j0 + q]) - 2.0 * acc;
    if (d2 < 0.0) d2 = 0.0;
    const float f = (float)sqrt(d2);
    distM[(((size_t)((b << 11) + i0 + r)) << 11) + j0 + q] = f;
    distM[(((size_t)((b << 11) + j0 + q)) << 11) + i0 + r] = f;
  }
}

// ---------- K4: wave-per-row radix select + fused mean (last block) -------
// grid 4096, block 256 (4 waves, one row each). After all kth stores, the
// last block to finish (atomic ticket, threadfence-protected) computes
// Rf[b] = mean(kth[b][:]) with the exact k_mean2048 reduction tree.
__global__ __launch_bounds__(256) void k_sel_mean(const float* __restrict__ dist,
                                                  float* __restrict__ kth,
                                                  unsigned* __restrict__ counter,
                                                  float* __restrict__ Rf) {
  __shared__ double lds[4];
  __shared__ int lastBlock;
  const int row = (blockIdx.x << 2) + (threadIdx.x >> 6);
  const int l = threadIdx.x & 63;
  const int t = threadIdx.x;
  const float4* r4 = (const float4*)(dist + ((size_t)row << 11));
  unsigned u[32];
  #pragma unroll
  for (int jj = 0; jj < 8; ++jj) {
    const float4 fv = r4[(jj << 6) + l];
    u[jj * 4 + 0] = __float_as_uint(fv.x);
    u[jj * 4 + 1] = __float_as_uint(fv.y);
    u[jj * 4 + 2] = __float_as_uint(fv.z);
    u[jj * 4 + 3] = __float_as_uint(fv.w);
  }
  unsigned pref = 0;
  for (int bit = 30; bit >= 0; --bit) {
    const unsigned mid = pref | (1u << bit);
    int c = 0;
    #pragma unroll
    for (int k = 0; k < 32; ++k)
      c += (int)__popcll(__ballot(u[k] < mid));
    if (c <= KSEL) pref = mid;
  }
  if (l == 0) kth[row] = __uint_as_float(pref);

  // ---- last-block-done fused mean ----
  __threadfence();                       // make kth stores device-visible
  __syncthreads();
  if (t == 0) {
    const unsigned done = atomicAdd(counter, 1u);
    lastBlock = (done == 4095u) ? 1 : 0;
  }
  __syncthreads();
  if (lastBlock) {
    for (int b = 0; b < BZ; ++b) {
      const float* p = kth + (b << 11);
      double s = 0.0;
      #pragma unroll
      for (int q = 0; q < 8; ++q) s += (double)p[t + q * 256];
      s = blockReduceD(s, lds);
      if (t == 0) Rf[b] = (float)(s * (1.0 / 2048.0));
      __syncthreads();
    }
  }
}

// ---------- K5: counts; samples by row scan, neighbors by king gather ----
__global__ __launch_bounds__(256) void k_count_geo(
    const float* __restrict__ dist, const float* __restrict__ Rf,
    float* __restrict__ samples, float* __restrict__ neigh,
    float* __restrict__ degree) {
  __shared__ int pS[4];
  const int bi = blockIdx.x;            // b*2048 + i
  const int b = bi >> 11, i = bi & 2047;
  const int t = threadIdx.x, w = t >> 6, l = t & 63;
  const float R = Rf[b];
  const float* drow = dist + ((size_t)bi << 11);
  const float4* d4 = (const float4*)drow + (t << 1);
  const float4 d0 = d4[0], d1 = d4[1];
  const float f[8] = {d0.x, d0.y, d0.z, d0.w, d1.x, d1.y, d1.z, d1.w};
  int sN = 0;
  #pragma unroll
  for (int q = 0; q < 8; ++q) sN += (int)__popcll(__ballot(f[q] < R));
  if (l == 0) pS[w] = sN;
  __syncthreads();
  if (t < 64) {
    bool inb = false, ok = false;
    if (l < 8) {
      const int m = (l < 4) ? l : l + 1;          // skip (0,0)
      const int di = m / 3 - 1, dj = m % 3 - 1;   // king-move offsets
      const int rj = (i >> 6) + di, cj = (i & 63) + dj;
      inb = ((unsigned)rj < 32u) && ((unsigned)cj < 64u);
      if (inb) {
        const float fv = drow[(rj << 6) + cj];
        ok = (fv != 0.0f) && (fv < R);
      }
    }
    const int nN = (int)__popcll(__ballot(ok));
    const int dc = (int)__popcll(__ballot(inb));
    if (t == 0) {
      samples[bi] = (float)(pS[0] + pS[1] + pS[2] + pS[3]);
      neigh[bi]   = (float)nN;
      if (b == 0) degree[i] = (float)dc;
    }
  }
}

// ---------- K6: mean(samples) + total_score + stable rank + mask ----------
__global__ __launch_bounds__(256) void k_rank_score(
    const float* __restrict__ samples, const float* __restrict__ neigh,
    const float* __restrict__ degree, float* __restrict__ score,
    float* __restrict__ mask) {
  __shared__ double lds[4];
  __shared__ float mfs;
  __shared__ float sc[NN];
  const int b = blockIdx.x >> 3, chunk = blockIdx.x & 7, t = threadIdx.x;
  const float* p = samples + (b << 11);
  double s = 0.0;
  #pragma unroll
  for (int q = 0; q < 8; ++q) s += (double)p[t + q * 256];
  s = blockReduceD(s, lds);
  if (t == 0) mfs = (float)(s * (1.0 / 2048.0));
  __syncthreads();
  const float mf = mfs;
  #pragma unroll
  for (int q = 0; q < 8; ++q) {
    const int i = t + q * 256;
    const int g = (b << 11) + i;
    const float sp = neigh[g] / degree[i];
    const float sv = p[i];
    const float tp = sv / (sv + mf);
    const float v = (2.0f - sp) - tp;
    sc[i] = v;
    if (chunk == 0) score[g] = v;
  }
  __syncthreads();
  const int i = chunk * 256 + t;
  const float si = sc[i];
  int less = 0, eqb = 0;
  for (int j = 0; j < NN; ++j) {
    const float sj = sc[j];
    less += (sj < si) ? 1 : 0;
    eqb  += ((sj == si) && (j < i)) ? 1 : 0;
  }
  mask[(b << 11) + i] = ((less + eqb) < KEEP) ? 1.0f : 0.0f;
}

// ---------- K7: out = data * mask ----------
__global__ __launch_bounds__(256) void k_apply(const float* __restrict__ data,
                                               const float* __restrict__ mask,
                                               float* __restrict__ out) {
  const int g = blockIdx.x * 256 + threadIdx.x;
  const float4 d = ((const float4*)data)[g];
  const int idx = g << 2;
  const int b = idx >> 18;
  const int w = idx & 2047;
  const float4 mk = *(const float4*)(mask + (b << 11) + w);
  float4 o;
  o.x = d.x * mk.x; o.y = d.y * mk.y; o.z = d.z * mk.z; o.w = d.w * mk.w;
  ((float4*)out)[g] = o;
}

extern "C" void kernel_launch(void* const* d_in, const int* in_sizes, int n_in,
                              void* d_out, int out_size, void* d_ws, size_t ws_size,
                              hipStream_t stream) {
  (void)in_sizes; (void)n_in; (void)out_size; (void)ws_size;
  const float* data = (const float*)d_in[0];
  float* out = (float*)d_out;

  float* xnT   = out;             // fp32 Xn staged in output, overwritten last
  float* score = out + 2097152;   // total_score output slot (8*2048)

  uint8_t* w = (uint8_t*)d_ws;
  double*   sq      = (double*)(w);            // 131072 B
  float*    kth     = (float*)(w + 131072);    // 65536 B
  float*    Rf      = (float*)(w + 196608);    // 32 B
  float*    samples = (float*)(w + 196672);    // 65536 B
  float*    neigh   = (float*)(w + 262208);    // 65536 B
  unsigned* counter = (unsigned*)(w + 327744); // 4 B
  float*    degree  = (float*)(w + 327808);    // 8192 B
  float*    mask    = (float*)(w + 336000);    // 65536 B

  const size_t panelBytes = (size_t)BZ * DDIM * NN * sizeof(double); // 16777216
  double* panelD = (double*)(w + 1048576);
  float*  distM  = (float*)(w + 1048576 + panelBytes);

  k_norm      <<<1024,  256, 0, stream>>>(data, xnT, panelD, counter);
  k_sq        <<<64,    256, 0, stream>>>(xnT, sq);
  k_gemm_sgpr <<<2304,  256, 0, stream>>>(xnT, panelD, sq, distM);
  k_sel_mean  <<<4096,  256, 0, stream>>>(distM, kth, counter, Rf);
  k_count_geo <<<16384, 256, 0, stream>>>(distM, Rf, samples, neigh, degree);
  k_rank_score<<<64,    256, 0, stream>>>(samples, neigh, degree, score, mask);
  k_apply     <<<2048,  256, 0, stream>>>(data, mask, out);
}

// Round 17
// 278.437 us; speedup vs baseline: 2.0109x; 2.0109x over previous
//
#include <hip/hip_runtime.h>
#include <math.h>

#define BZ   8
#define DDIM 128
#define NN   2048
#define KSEL 30
#define KEEP 1024
#define ROWS 8

// ---------- block reduction (blockDim == 256) ----------
__device__ __forceinline__ double blockReduceD(double x, double* lds) {
  #pragma unroll
  for (int off = 32; off; off >>= 1) x += __shfl_down(x, off, 64);
  int wv = threadIdx.x >> 6;
  __syncthreads();
  if ((threadIdx.x & 63) == 0) lds[wv] = x;
  __syncthreads();
  return lds[0] + lds[1] + lds[2] + lds[3];
}

// ---------- K1: normalize -> fp32 xnT + fp64 row panel [b][g][d][8] -------
__global__ __launch_bounds__(256) void k_norm(const float* __restrict__ data,
                                              float* __restrict__ xnT,
                                              double* __restrict__ panelD) {
  __shared__ double lds[4];
  __shared__ float msd[2];
  const int blk = blockIdx.x;          // b*128 + d
  const int t = threadIdx.x;
  const float* src = data + (size_t)blk * NN;
  float v[8];
  double s = 0.0, s2 = 0.0;
  #pragma unroll
  for (int q = 0; q < 8; ++q) {
    v[q] = src[t + q * 256];
    double d = (double)v[q];
    s += d;
    s2 = fma(d, d, s2);
  }
  s  = blockReduceD(s, lds);
  s2 = blockReduceD(s2, lds);
  if (t == 0) {
    double mean = s * (1.0 / 2048.0);
    double var = (s2 - s * mean) / 2047.0;
    if (var < 0.0) var = 0.0;
    msd[0] = (float)mean;
    msd[1] = (float)sqrt(var);
  }
  __syncthreads();
  const float mean = msd[0];
  const float den = msd[1] + 1e-6f;
  const int b = blk >> 7, d = blk & 127;
  #pragma unroll
  for (int q = 0; q < 8; ++q) {
    const int n = t + q * 256;
    const float xn = (v[q] - mean) / den;   // fp32 rounding point
    xnT[(size_t)blk * NN + n] = xn;
    panelD[(size_t)(b * 256 + (n >> 3)) * 1024 + d * 8 + (n & 7)] = (double)xn;
  }
}

// ---------- K2: sq[b][n] = sum_d Xn^2 (fp64 chain, fp32 input) ----------
__global__ __launch_bounds__(256) void k_sq(const float* __restrict__ xnT,
                                            double* __restrict__ sq) {
  const int g = blockIdx.x * 256 + threadIdx.x;
  const int b = g >> 11, n = g & 2047;
  const float* X = xnT + (size_t)b * DDIM * NN + n;
  double s = 0.0;
  for (int d = 0; d < DDIM; ++d) {
    double x = (double)X[(size_t)d * NN];
    s = fma(x, x, s);
  }
  sq[g] = s;
}

// ---------- K3: cyclic-halved symmetric fp64 GEMM, SGPR rows --------------
// Blocks [0,2048): b=blk&7 (XCD pin), g=blk>>3; rows [8g,8g+8), cols cyclic
// window [8g, 8g+1024). Rows from fp64 panel (block-uniform -> s_load, SGPR
// fma operand); cols fp32 float4 + exact widen. Separation-128 antipodal
// tiles: blocks [2048,2304). Proven 130.5 us / absmax 0.0 (rounds 9,12-16).
__global__ __launch_bounds__(256, 4) void k_gemm_sgpr(
    const float* __restrict__ xnT, const double* __restrict__ panelD,
    const double* __restrict__ sq, float* __restrict__ distM) {
  const int t = threadIdx.x;
  if (blockIdx.x < 2048) {
    const int b = blockIdx.x & 7;
    const int g = blockIdx.x >> 3;
    const int i0 = g << 3;
    const int c = (i0 + (t << 2)) & (NN - 1);
    const float*  cp = xnT + (size_t)b * DDIM * NN + c;
    const double* rp = panelD + ((size_t)(b * 256 + g) << 10);
    double acc[ROWS][4];
    #pragma unroll
    for (int r = 0; r < ROWS; ++r)
      #pragma unroll
      for (int q = 0; q < 4; ++q) acc[r][q] = 0.0;
    #pragma unroll 2
    for (int d = 0; d < DDIM; ++d) {
      const float4 c0 = *(const float4*)(cp + ((size_t)d << 11));
      const double cd0 = (double)c0.x, cd1 = (double)c0.y;
      const double cd2 = (double)c0.z, cd3 = (double)c0.w;
      #pragma unroll
      for (int r = 0; r < ROWS; ++r) {
        const double rv = rp[(d << 3) + r];   // uniform -> s_load
        acc[r][0] = fma(rv, cd0, acc[r][0]);
        acc[r][1] = fma(rv, cd1, acc[r][1]);
        acc[r][2] = fma(rv, cd2, acc[r][2]);
        acc[r][3] = fma(rv, cd3, acc[r][3]);
      }
    }
    const double* sqb = sq + (b << 11);
    const double sqc0 = sqb[c], sqc1 = sqb[c + 1], sqc2 = sqb[c + 2], sqc3 = sqb[c + 3];
    float f[ROWS][4];
    #pragma unroll
    for (int r = 0; r < ROWS; ++r) {
      const double sqi = sqb[i0 + r];
      double d2;
      d2 = (sqi + sqc0) - 2.0 * acc[r][0]; if (d2 < 0.0) d2 = 0.0; f[r][0] = (float)sqrt(d2);
      d2 = (sqi + sqc1) - 2.0 * acc[r][1]; if (d2 < 0.0) d2 = 0.0; f[r][1] = (float)sqrt(d2);
      d2 = (sqi + sqc2) - 2.0 * acc[r][2]; if (d2 < 0.0) d2 = 0.0; f[r][2] = (float)sqrt(d2);
      d2 = (sqi + sqc3) - 2.0 * acc[r][3]; if (d2 < 0.0) d2 = 0.0; f[r][3] = (float)sqrt(d2);
      *(float4*)(distM + (((size_t)((b << 11) + i0 + r)) << 11) + c) =
          make_float4(f[r][0], f[r][1], f[r][2], f[r][3]);
    }
    #pragma unroll
    for (int q = 0; q < 4; ++q) {
      float* trow = distM + (((size_t)((b << 11) + c + q)) << 11) + i0;
      *(float4*)(trow)     = make_float4(f[0][q], f[1][q], f[2][q], f[3][q]);
      *(float4*)(trow + 4) = make_float4(f[4][q], f[5][q], f[6][q], f[7][q]);
    }
  } else {
    const int a = (blockIdx.x - 2048) * 4 + (t >> 6);
    const int b = a & 7;
    const int g = a >> 3;
    const int i0 = g << 3;
    const int j0 = i0 + 1024;
    const int l = t & 63;
    const int r = l >> 3, q = l & 7;
    const double* rp = panelD + ((size_t)(b * 256 + g) << 10);
    const float*  cp = xnT + (size_t)b * DDIM * NN + j0 + q;
    double acc = 0.0;
    for (int d = 0; d < DDIM; ++d)
      acc = fma(rp[(d << 3) + r], (double)cp[(size_t)d << 11], acc);
    const double* sqb = sq + (b << 11);
    double d2 = (sqb[i0 + r] + sqb[j0 + q]) - 2.0 * acc;
    if (d2 < 0.0) d2 = 0.0;
    const float f = (float)sqrt(d2);
    distM[(((size_t)((b << 11) + i0 + r)) << 11) + j0 + q] = f;
    distM[(((size_t)((b << 11) + j0 + q)) << 11) + i0 + r] = f;
  }
}

// ---------- K4: wave-per-row radix select (count(u<mid) form) ----------
__global__ __launch_bounds__(256) void k_sel(const float* __restrict__ dist,
                                             float* __restrict__ kth) {
  const int row = (blockIdx.x << 2) + (threadIdx.x >> 6);
  const int l = threadIdx.x & 63;
  const float4* r4 = (const float4*)(dist + ((size_t)row << 11));
  unsigned u[32];
  #pragma unroll
  for (int jj = 0; jj < 8; ++jj) {
    const float4 fv = r4[(jj << 6) + l];
    u[jj * 4 + 0] = __float_as_uint(fv.x);
    u[jj * 4 + 1] = __float_as_uint(fv.y);
    u[jj * 4 + 2] = __float_as_uint(fv.z);
    u[jj * 4 + 3] = __float_as_uint(fv.w);
  }
  unsigned pref = 0;
  for (int bit = 30; bit >= 0; --bit) {
    const unsigned mid = pref | (1u << bit);
    int c = 0;
    #pragma unroll
    for (int k = 0; k < 32; ++k)
      c += (int)__popcll(__ballot(u[k] < mid));
    if (c <= KSEL) pref = mid;
  }
  if (l == 0) kth[row] = __uint_as_float(pref);
}

// ---------- K5: mean of 2048 floats -> float ----------
__global__ __launch_bounds__(256) void k_mean2048(const float* __restrict__ in,
                                                  float* __restrict__ out) {
  __shared__ double lds[4];
  const int b = blockIdx.x, t = threadIdx.x;
  const float* p = in + (b << 11);
  double s = 0.0;
  #pragma unroll
  for (int q = 0; q < 8; ++q) s += (double)p[t + q * 256];
  s = blockReduceD(s, lds);
  if (t == 0) out[b] = (float)(s * (1.0 / 2048.0));
}

// ---------- K6: counts; samples by row scan, neighbors by king gather ----
__global__ __launch_bounds__(256) void k_count_geo(
    const float* __restrict__ dist, const float* __restrict__ Rf,
    float* __restrict__ samples, float* __restrict__ neigh,
    float* __restrict__ degree) {
  __shared__ int pS[4];
  const int bi = blockIdx.x;            // b*2048 + i
  const int b = bi >> 11, i = bi & 2047;
  const int t = threadIdx.x, w = t >> 6, l = t & 63;
  const float R = Rf[b];
  const float* drow = dist + ((size_t)bi << 11);
  const float4* d4 = (const float4*)drow + (t << 1);
  const float4 d0 = d4[0], d1 = d4[1];
  const float f[8] = {d0.x, d0.y, d0.z, d0.w, d1.x, d1.y, d1.z, d1.w};
  int sN = 0;
  #pragma unroll
  for (int q = 0; q < 8; ++q) sN += (int)__popcll(__ballot(f[q] < R));
  if (l == 0) pS[w] = sN;
  __syncthreads();
  if (t < 64) {
    bool inb = false, ok = false;
    if (l < 8) {
      const int m = (l < 4) ? l : l + 1;          // skip (0,0)
      const int di = m / 3 - 1, dj = m % 3 - 1;   // king-move offsets
      const int rj = (i >> 6) + di, cj = (i & 63) + dj;
      inb = ((unsigned)rj < 32u) && ((unsigned)cj < 64u);
      if (inb) {
        const float fv = drow[(rj << 6) + cj];
        ok = (fv != 0.0f) && (fv < R);
      }
    }
    const int nN = (int)__popcll(__ballot(ok));
    const int dc = (int)__popcll(__ballot(inb));
    if (t == 0) {
      samples[bi] = (float)(pS[0] + pS[1] + pS[2] + pS[3]);
      neigh[bi]   = (float)nN;
      if (b == 0) degree[i] = (float)dc;
    }
  }
}

// ---------- K7: mean(samples) + total_score + stable rank + mask ----------
__global__ __launch_bounds__(256) void k_rank_score(
    const float* __restrict__ samples, const float* __restrict__ neigh,
    const float* __restrict__ degree, float* __restrict__ score,
    float* __restrict__ mask) {
  __shared__ double lds[4];
  __shared__ float mfs;
  __shared__ float sc[NN];
  const int b = blockIdx.x >> 3, chunk = blockIdx.x & 7, t = threadIdx.x;
  const float* p = samples + (b << 11);
  double s = 0.0;
  #pragma unroll
  for (int q = 0; q < 8; ++q) s += (double)p[t + q * 256];
  s = blockReduceD(s, lds);
  if (t == 0) mfs = (float)(s * (1.0 / 2048.0));
  __syncthreads();
  const float mf = mfs;
  #pragma unroll
  for (int q = 0; q < 8; ++q) {
    const int i = t + q * 256;
    const int g = (b << 11) + i;
    const float sp = neigh[g] / degree[i];
    const float sv = p[i];
    const float tp = sv / (sv + mf);
    const float v = (2.0f - sp) - tp;
    sc[i] = v;
    if (chunk == 0) score[g] = v;
  }
  __syncthreads();
  const int i = chunk * 256 + t;
  const float si = sc[i];
  int less = 0, eqb = 0;
  for (int j = 0; j < NN; ++j) {
    const float sj = sc[j];
    less += (sj < si) ? 1 : 0;
    eqb  += ((sj == si) && (j < i)) ? 1 : 0;
  }
  mask[(b << 11) + i] = ((less + eqb) < KEEP) ? 1.0f : 0.0f;
}

// ---------- K8: out = data * mask ----------
__global__ __launch_bounds__(256) void k_apply(const float* __restrict__ data,
                                               const float* __restrict__ mask,
                                               float* __restrict__ out) {
  const int g = blockIdx.x * 256 + threadIdx.x;
  const float4 d = ((const float4*)data)[g];
  const int idx = g << 2;
  const int b = idx >> 18;
  const int w = idx & 2047;
  const float4 mk = *(const float4*)(mask + (b << 11) + w);
  float4 o;
  o.x = d.x * mk.x; o.y = d.y * mk.y; o.z = d.z * mk.z; o.w = d.w * mk.w;
  ((float4*)out)[g] = o;
}

extern "C" void kernel_launch(void* const* d_in, const int* in_sizes, int n_in,
                              void* d_out, int out_size, void* d_ws, size_t ws_size,
                              hipStream_t stream) {
  (void)in_sizes; (void)n_in; (void)out_size; (void)ws_size;
  const float* data = (const float*)d_in[0];
  float* out = (float*)d_out;

  float* xnT   = out;             // fp32 Xn staged in output, overwritten last
  float* score = out + 2097152;   // total_score output slot (8*2048)

  uint8_t* w = (uint8_t*)d_ws;
  double* sq      = (double*)(w);            // 131072 B
  float*  kth     = (float*)(w + 131072);    // 65536 B
  float*  Rf      = (float*)(w + 196608);    // 32 B
  float*  samples = (float*)(w + 196672);    // 65536 B
  float*  neigh   = (float*)(w + 262208);    // 65536 B
  float*  degree  = (float*)(w + 327808);    // 8192 B
  float*  mask    = (float*)(w + 336000);    // 65536 B

  const size_t panelBytes = (size_t)BZ * DDIM * NN * sizeof(double); // 16777216
  double* panelD = (double*)(w + 1048576);
  float*  distM  = (float*)(w + 1048576 + panelBytes);

  k_norm      <<<1024,  256, 0, stream>>>(data, xnT, panelD);
  k_sq        <<<64,    256, 0, stream>>>(xnT, sq);
  k_gemm_sgpr <<<2304,  256, 0, stream>>>(xnT, panelD, sq, distM);
  k_sel       <<<4096,  256, 0, stream>>>(distM, kth);
  k_mean2048  <<<8,     256, 0, stream>>>(kth, Rf);
  k_count_geo <<<16384, 256, 0, stream>>>(distM, Rf, samples, neigh, degree);
  k_rank_score<<<64,    256, 0, stream>>>(samples, neigh, degree, score, mask);
  k_apply     <<<2048,  256, 0, stream>>>(data, mask, out);
}